// Round 4
// baseline (1812.217 us; speedup 1.0000x reference)
//
#include <hip/hip_runtime.h>

#define N_NODES 100000
#define E_EDGES 3200000
#define F_IN    512
#define C_OUT   64
#define NB      782      // buckets: node >> 7 (128 nodes per bucket)
#define CAP     5120     // bucket capacity (mean 4092, sigma 64 -> 16 sigma)
#define TILE    16384    // edges per block in P2
#define NTILE   196      // ceil(E / TILE)

typedef __bf16 bf16x8 __attribute__((ext_vector_type(8)));
typedef float  f32x4  __attribute__((ext_vector_type(4)));
typedef float  f32x2  __attribute__((ext_vector_type(2)));

// fp32 -> bf16 (round-to-nearest-even), bit-level
static __device__ __forceinline__ unsigned short f2bf(float f) {
    unsigned int u = __float_as_uint(f);
    u = (u + 0x7FFFu + ((u >> 16) & 1u)) >> 16;
    return (unsigned short)u;
}
// bf16 bits -> fp32 (exact)
static __device__ __forceinline__ float bf2f(unsigned short b) {
    return __uint_as_float(((unsigned int)b) << 16);
}
// fp32 -> fp8 e4m3 (OCP on gfx950), single byte via HW convert
static __device__ __forceinline__ unsigned char f32_to_fp8(float v) {
    return (unsigned char)(__builtin_amdgcn_cvt_pk_fp8_f32(v, v, 0, false) & 0xFF);
}
// 2 packed fp8 -> 2 fp32 via HW convert (same HW format as encode)
static __device__ __forceinline__ f32x2 fp8x2_to_f32(unsigned short u) {
    return __builtin_amdgcn_cvt_pk_f32_fp8((int)(unsigned int)u, false);
}

// ---------------------------------------------------------------------------
// zero: out-degree array + bucket cursors
// ---------------------------------------------------------------------------
__global__ __launch_bounds__(512) void zero_kernel(int* __restrict__ deg_src,
                                                   int* __restrict__ cursor_d) {
    int i = blockIdx.x * 512 + threadIdx.x;
    if (i < N_NODES) deg_src[i] = 0;
    if (i < NB) cursor_d[i] = 0;
}

// ---------------------------------------------------------------------------
// P2: two-pass dst-partition into fixed-capacity bucket regions + global
// out-degree atomics (random over 100K ints, no-return -> fire-and-forget).
//   tmp[b*CAP..] : u32 (dst&127)<<24 | src
// ---------------------------------------------------------------------------
__global__ __launch_bounds__(512) void p2_part(const int* __restrict__ src,
                                               const int* __restrict__ dst,
                                               int* __restrict__ cursor_d,
                                               int* __restrict__ deg_src,
                                               unsigned int* __restrict__ tmp) {
    __shared__ int cd[NB];
    __shared__ int bd[NB];
    int t = threadIdx.x;
    for (int j = t; j < NB; j += 512) cd[j] = 0;
    __syncthreads();
    int tb = blockIdx.x * TILE;
    // --- pass A: count ---
    #pragma unroll 4
    for (int i = 0; i < 32; ++i) {
        int e = tb + i * 512 + t;
        if (e < E_EDGES) {
            atomicAdd(&cd[dst[e] >> 7], 1);
            atomicAdd(&deg_src[src[e]], 1);
        }
    }
    __syncthreads();
    // --- reserve contiguous runs ---
    for (int j = t; j < NB; j += 512) {
        int c = cd[j];
        bd[j] = j * CAP + (c ? atomicAdd(&cursor_d[j], c) : 0);
        cd[j] = 0;
    }
    __syncthreads();
    // --- pass B: write (re-read src/dst, L2-hot) ---
    #pragma unroll 4
    for (int i = 0; i < 32; ++i) {
        int e = tb + i * 512 + t;
        if (e < E_EDGES) {
            int s = src[e], d = dst[e];
            int db = d >> 7;
            int p = atomicAdd(&cd[db], 1);
            tmp[bd[db] + p] = ((unsigned int)(d & 127) << 24) | (unsigned int)s;
        }
    }
}

// ---------------------------------------------------------------------------
// GEMM (bf16 MFMA), 256 rows/block, 4 M-tiles per wave. Writes h0b (bf16,
// channel-ordered, for teleport term) AND h8 with norm_src pre-folded.
// h8 byte layout is INTERLEAVED for the aggregator: byte 2i = channel i,
// byte 2i+1 = channel i+32 (i in 0..31) -> one ushort gather per lane yields
// channels (c2, c2+32), whose LDS adds are bank-conflict-free.
// ---------------------------------------------------------------------------
__global__ __launch_bounds__(256) void gemm_kernel(const float* __restrict__ A,
                                                   const float* __restrict__ W,
                                                   const float* __restrict__ bias,
                                                   const int* __restrict__ deg_src,
                                                   unsigned short* __restrict__ h0b,
                                                   unsigned char* __restrict__ h8) {
    __shared__ unsigned short Wl[64 * 520];   // 66560 B

    const int tid  = threadIdx.x;
    const int w    = tid >> 6;
    const int lane = tid & 63;
    const int cl   = lane & 15;
    const int quad = lane >> 4;
    const int row0 = blockIdx.x * 256;

    #pragma unroll 8
    for (int j = 0; j < 32; ++j) {
        int e4 = (j * 256 + tid) * 4;
        float4 wv = *reinterpret_cast<const float4*>(&W[e4]);
        int c = e4 >> 9;
        int k = e4 & 511;
        unsigned short* d = &Wl[c * 520 + k];
        d[0] = f2bf(wv.x); d[1] = f2bf(wv.y); d[2] = f2bf(wv.z); d[3] = f2bf(wv.w);
    }
    __syncthreads();

    const float* aptr[4];
    #pragma unroll
    for (int mt = 0; mt < 4; ++mt) {
        int arow = row0 + mt * 64 + w * 16 + cl;
        if (arow >= N_NODES) arow = N_NODES - 1;
        aptr[mt] = A + (size_t)arow * F_IN + quad * 8;
    }

    f32x4 acc0[4], acc1[4], acc2[4], acc3[4];
    #pragma unroll
    for (int mt = 0; mt < 4; ++mt) {
        acc0[mt] = (f32x4){0.f, 0.f, 0.f, 0.f};
        acc1[mt] = (f32x4){0.f, 0.f, 0.f, 0.f};
        acc2[mt] = (f32x4){0.f, 0.f, 0.f, 0.f};
        acc3[mt] = (f32x4){0.f, 0.f, 0.f, 0.f};
    }

    for (int k0 = 0; k0 < F_IN; k0 += 32) {
        bf16x8 af[4];
        #pragma unroll
        for (int mt = 0; mt < 4; ++mt) {
            float4 p = *reinterpret_cast<const float4*>(aptr[mt] + k0);
            float4 q = *reinterpret_cast<const float4*>(aptr[mt] + k0 + 4);
            af[mt][0] = (__bf16)p.x; af[mt][1] = (__bf16)p.y;
            af[mt][2] = (__bf16)p.z; af[mt][3] = (__bf16)p.w;
            af[mt][4] = (__bf16)q.x; af[mt][5] = (__bf16)q.y;
            af[mt][6] = (__bf16)q.z; af[mt][7] = (__bf16)q.w;
        }

        const unsigned short* wb = &Wl[k0 + quad * 8];
        bf16x8 b0 = *reinterpret_cast<const bf16x8*>(wb + (cl +  0) * 520);
        bf16x8 b1 = *reinterpret_cast<const bf16x8*>(wb + (cl + 16) * 520);
        bf16x8 b2 = *reinterpret_cast<const bf16x8*>(wb + (cl + 32) * 520);
        bf16x8 b3 = *reinterpret_cast<const bf16x8*>(wb + (cl + 48) * 520);

        #pragma unroll
        for (int mt = 0; mt < 4; ++mt) {
            acc0[mt] = __builtin_amdgcn_mfma_f32_16x16x32_bf16(af[mt], b0, acc0[mt], 0, 0, 0);
            acc1[mt] = __builtin_amdgcn_mfma_f32_16x16x32_bf16(af[mt], b1, acc1[mt], 0, 0, 0);
            acc2[mt] = __builtin_amdgcn_mfma_f32_16x16x32_bf16(af[mt], b2, acc2[mt], 0, 0, 0);
            acc3[mt] = __builtin_amdgcn_mfma_f32_16x16x32_bf16(af[mt], b3, acc3[mt], 0, 0, 0);
        }
    }

    float bias0 = bias[cl +  0];
    float bias1 = bias[cl + 16];
    float bias2 = bias[cl + 32];
    float bias3 = bias[cl + 48];
    #pragma unroll
    for (int mt = 0; mt < 4; ++mt) {
        #pragma unroll
        for (int r = 0; r < 4; ++r) {
            int row = row0 + mt * 64 + w * 16 + quad * 4 + r;
            if (row < N_NODES) {
                float v0 = acc0[mt][r] + bias0;   // channel cl
                float v1 = acc1[mt][r] + bias1;   // channel cl+16
                float v2 = acc2[mt][r] + bias2;   // channel cl+32
                float v3 = acc3[mt][r] + bias3;   // channel cl+48
                unsigned short* o = &h0b[(size_t)row * C_OUT + cl];
                o[ 0] = f2bf(v0);
                o[16] = f2bf(v1);
                o[32] = f2bf(v2);
                o[48] = f2bf(v3);
                int dg = deg_src[row];
                float ns = rsqrtf((float)(dg < 1 ? 1 : dg));
                unsigned char* o8 = &h8[(size_t)row * C_OUT];
                // interleaved: byte 2i = ch i, byte 2i+1 = ch i+32
                o8[2 * cl     ] = f32_to_fp8(v0 * ns);   // ch cl
                o8[2 * cl + 32] = f32_to_fp8(v1 * ns);   // ch cl+16 -> byte 2(cl+16)
                o8[2 * cl +  1] = f32_to_fp8(v2 * ns);   // ch cl+32
                o8[2 * cl + 33] = f32_to_fp8(v3 * ns);   // ch cl+48
            }
        }
    }
}

// ---------------------------------------------------------------------------
// agg: block b owns the 128 nodes [128b, 128b+128). 32KB LDS fp32
// accumulator [128][64]. The gather batches are pinned with inline asm:
// 8 global loads + one s_waitcnt inside a single asm volatile block, so the
// scheduler CANNOT re-roll them into per-edge dependent chains (rounds 1/3
// failure: VGPR=20, MLP=1, ~800cy/edge serial). Outputs of the asm block are
// valid on exit (waitcnt is inside), no sched_barrier hazard.
// ---------------------------------------------------------------------------
__global__ __launch_bounds__(512, 4) void agg_kernel(const unsigned int* __restrict__ tmp,
                                                     const int* __restrict__ cursor_d,
                                                     const unsigned char* __restrict__ h8,
                                                     const unsigned short* __restrict__ h0b,
                                                     float* __restrict__ out) {
    __shared__ float acc[128 * 64];   // 32 KB
    __shared__ int   cnt[128];
    __shared__ float ndl[128];

    int t = threadIdx.x;
    int b = blockIdx.x;

    for (int q = t; q < 128 * 64 / 4; q += 512)
        reinterpret_cast<f32x4*>(acc)[q] = (f32x4){0.f, 0.f, 0.f, 0.f};
    if (t < 128) cnt[t] = 0;
    __syncthreads();

    int nE = cursor_d[b];
    const unsigned int* te = tmp + (size_t)b * CAP;

    // in-degree histogram (for norm_dst): ~8 coalesced iters
    for (int e = t; e < nE; e += 512)
        atomicAdd(&cnt[te[e] >> 24], 1);

    int w    = t >> 6;
    int lane = t & 63;
    int half = lane >> 5;          // edge parity within chunk
    int c2   = lane & 31;          // channel (c2, c2+32)
    const unsigned short* h8p = reinterpret_cast<const unsigned short*>(h8); // row stride 32

    int nC = nE >> 4;              // full 16-edge chunks
    for (int j = w; j < nC; j += 8) {
        const unsigned int* ep = te + ((j << 4) + half);
        unsigned int v0, v1, v2, v3, v4, v5, v6, v7;
        asm volatile(
            "global_load_dword %0, %8, off\n\t"
            "global_load_dword %1, %8, off offset:8\n\t"
            "global_load_dword %2, %8, off offset:16\n\t"
            "global_load_dword %3, %8, off offset:24\n\t"
            "global_load_dword %4, %8, off offset:32\n\t"
            "global_load_dword %5, %8, off offset:40\n\t"
            "global_load_dword %6, %8, off offset:48\n\t"
            "global_load_dword %7, %8, off offset:56\n\t"
            "s_waitcnt vmcnt(0)"
            : "=&v"(v0), "=&v"(v1), "=&v"(v2), "=&v"(v3),
              "=&v"(v4), "=&v"(v5), "=&v"(v6), "=&v"(v7)
            : "v"(ep)
            : "memory");

        const unsigned short* p0 = h8p + ((v0 & 0xFFFFFFu) << 5) + c2;
        const unsigned short* p1 = h8p + ((v1 & 0xFFFFFFu) << 5) + c2;
        const unsigned short* p2 = h8p + ((v2 & 0xFFFFFFu) << 5) + c2;
        const unsigned short* p3 = h8p + ((v3 & 0xFFFFFFu) << 5) + c2;
        const unsigned short* p4 = h8p + ((v4 & 0xFFFFFFu) << 5) + c2;
        const unsigned short* p5 = h8p + ((v5 & 0xFFFFFFu) << 5) + c2;
        const unsigned short* p6 = h8p + ((v6 & 0xFFFFFFu) << 5) + c2;
        const unsigned short* p7 = h8p + ((v7 & 0xFFFFFFu) << 5) + c2;

        unsigned int u0, u1, u2, u3, u4, u5, u6, u7;
        asm volatile(
            "global_load_ushort %0, %8, off\n\t"
            "global_load_ushort %1, %9, off\n\t"
            "global_load_ushort %2, %10, off\n\t"
            "global_load_ushort %3, %11, off\n\t"
            "global_load_ushort %4, %12, off\n\t"
            "global_load_ushort %5, %13, off\n\t"
            "global_load_ushort %6, %14, off\n\t"
            "global_load_ushort %7, %15, off\n\t"
            "s_waitcnt vmcnt(0)"
            : "=&v"(u0), "=&v"(u1), "=&v"(u2), "=&v"(u3),
              "=&v"(u4), "=&v"(u5), "=&v"(u6), "=&v"(u7)
            : "v"(p0), "v"(p1), "v"(p2), "v"(p3),
              "v"(p4), "v"(p5), "v"(p6), "v"(p7)
            : "memory");

        f32x2 f0 = fp8x2_to_f32((unsigned short)u0);
        f32x2 f1 = fp8x2_to_f32((unsigned short)u1);
        f32x2 f2 = fp8x2_to_f32((unsigned short)u2);
        f32x2 f3 = fp8x2_to_f32((unsigned short)u3);
        f32x2 f4 = fp8x2_to_f32((unsigned short)u4);
        f32x2 f5 = fp8x2_to_f32((unsigned short)u5);
        f32x2 f6 = fp8x2_to_f32((unsigned short)u6);
        f32x2 f7 = fp8x2_to_f32((unsigned short)u7);
        float* a0 = &acc[(int)((v0 >> 24) << 6) + c2];
        float* a1 = &acc[(int)((v1 >> 24) << 6) + c2];
        float* a2 = &acc[(int)((v2 >> 24) << 6) + c2];
        float* a3 = &acc[(int)((v3 >> 24) << 6) + c2];
        float* a4 = &acc[(int)((v4 >> 24) << 6) + c2];
        float* a5 = &acc[(int)((v5 >> 24) << 6) + c2];
        float* a6 = &acc[(int)((v6 >> 24) << 6) + c2];
        float* a7 = &acc[(int)((v7 >> 24) << 6) + c2];
        atomicAdd(a0,      f0[0]); atomicAdd(a0 + 32, f0[1]);
        atomicAdd(a1,      f1[0]); atomicAdd(a1 + 32, f1[1]);
        atomicAdd(a2,      f2[0]); atomicAdd(a2 + 32, f2[1]);
        atomicAdd(a3,      f3[0]); atomicAdd(a3 + 32, f3[1]);
        atomicAdd(a4,      f4[0]); atomicAdd(a4 + 32, f4[1]);
        atomicAdd(a5,      f5[0]); atomicAdd(a5 + 32, f5[1]);
        atomicAdd(a6,      f6[0]); atomicAdd(a6 + 32, f6[1]);
        atomicAdd(a7,      f7[0]); atomicAdd(a7 + 32, f7[1]);
    }
    // leftover (< 16 edges): one edge per 32-thread group, single parallel step
    {
        int base = nC << 4;
        int lidx = t >> 5;         // 0..15
        int lc2  = t & 31;
        int e = base + lidx;
        if (e < nE) {
            unsigned int v = te[e];
            unsigned short u = h8p[(v & 0xFFFFFFu) * 32 + lc2];
            f32x2 f = fp8x2_to_f32(u);
            float* a = &acc[(int)((v >> 24) << 6) + lc2];
            atomicAdd(a,      f[0]);
            atomicAdd(a + 32, f[1]);
        }
    }

    __syncthreads();
    if (t < 128) {
        int dg = cnt[t];
        ndl[t] = rsqrtf((float)(dg < 1 ? 1 : dg));   // dg==0 -> nd=1 (acc=0)
    }
    __syncthreads();

    const unsigned int* h32 = reinterpret_cast<const unsigned int*>(h0b); // row stride 32
    for (int p = t; p < 128 * 32; p += 512) {
        int nl = p >> 5;
        int q  = p & 31;
        int node = (b << 7) + nl;
        if (node < N_NODES) {
            unsigned int hu = h32[(size_t)node * 32 + q];
            float nd = ndl[nl];
            float2 r;
            r.x = 0.8f * nd * acc[(nl << 6) + 2 * q]     + 0.2f * bf2f((unsigned short)hu);
            r.y = 0.8f * nd * acc[(nl << 6) + 2 * q + 1] + 0.2f * bf2f((unsigned short)(hu >> 16));
            *reinterpret_cast<float2*>(&out[(size_t)node * C_OUT + 2 * q]) = r;
        }
    }
}

// ---------------------------------------------------------------------------
extern "C" void kernel_launch(void* const* d_in, const int* in_sizes, int n_in,
                              void* d_out, int out_size, void* d_ws, size_t ws_size,
                              hipStream_t stream) {
    const float* in_feat = (const float*)d_in[0];   // [N, 512]
    const float* W       = (const float*)d_in[1];   // [64, 512]
    const float* bias    = (const float*)d_in[2];   // [64]
    const int*   src     = (const int*)d_in[3];     // [E]
    const int*   dst     = (const int*)d_in[4];     // [E]
    float* out = (float*)d_out;                     // [N, 64]

    // workspace layout (no aliasing; ~36MB of ~800MB):
    char* p = (char*)d_ws;
    unsigned short* h0b = (unsigned short*)p;  p += (size_t)N_NODES * C_OUT * 2;   // 12.8MB
    unsigned char*  h8  = (unsigned char*)p;   p += (size_t)N_NODES * C_OUT;       // 6.4MB
    unsigned int*   tmp = (unsigned int*)p;    p += (size_t)NB * CAP * 4;          // 16MB
    int*   deg_src  = (int*)p;                 p += (size_t)N_NODES * 4;           // 0.4MB
    int*   cursor_d = (int*)p;

    zero_kernel<<<(N_NODES + 511) / 512, 512, 0, stream>>>(deg_src, cursor_d);
    p2_part<<<NTILE, 512, 0, stream>>>(src, dst, cursor_d, deg_src, tmp);
    gemm_kernel<<<(N_NODES + 255) / 256, 256, 0, stream>>>(in_feat, W, bias,
                                                           deg_src, h0b, h8);
    agg_kernel<<<NB, 512, 0, stream>>>(tmp, cursor_d, h8, h0b, out);
}

// Round 5
// 532.161 us; speedup vs baseline: 3.4054x; 3.4054x over previous
//
#include <hip/hip_runtime.h>

#define N_NODES 100000
#define E_EDGES 3200000
#define F_IN    512
#define C_OUT   64
#define NB      782      // buckets: node >> 7 (128 nodes per bucket)
#define CAP     5120     // bucket capacity (mean 4092, sigma 64 -> 16 sigma)
#define TILE    16384    // edges per block in P2
#define NTILE   196      // ceil(E / TILE)

typedef __bf16 bf16x8 __attribute__((ext_vector_type(8)));
typedef float  f32x4  __attribute__((ext_vector_type(4)));
typedef float  f32x2  __attribute__((ext_vector_type(2)));

// fp32 -> bf16 (round-to-nearest-even), bit-level
static __device__ __forceinline__ unsigned short f2bf(float f) {
    unsigned int u = __float_as_uint(f);
    u = (u + 0x7FFFu + ((u >> 16) & 1u)) >> 16;
    return (unsigned short)u;
}
// bf16 bits -> fp32 (exact)
static __device__ __forceinline__ float bf2f(unsigned short b) {
    return __uint_as_float(((unsigned int)b) << 16);
}
// fp32 -> fp8 e4m3 (OCP on gfx950), single byte via HW convert
static __device__ __forceinline__ unsigned char f32_to_fp8(float v) {
    return (unsigned char)(__builtin_amdgcn_cvt_pk_fp8_f32(v, v, 0, false) & 0xFF);
}
// 2 packed fp8 -> 2 fp32 via HW convert (same HW format as encode)
static __device__ __forceinline__ f32x2 fp8x2_to_f32(unsigned short u) {
    return __builtin_amdgcn_cvt_pk_f32_fp8((int)(unsigned int)u, false);
}

// ---------------------------------------------------------------------------
// zero: out-degree array + bucket cursors
// ---------------------------------------------------------------------------
__global__ __launch_bounds__(512) void zero_kernel(int* __restrict__ deg_src,
                                                   int* __restrict__ cursor_d) {
    int i = blockIdx.x * 512 + threadIdx.x;
    if (i < N_NODES) deg_src[i] = 0;
    if (i < NB) cursor_d[i] = 0;
}

// ---------------------------------------------------------------------------
// P2: two-pass dst-partition into fixed-capacity bucket regions + global
// out-degree atomics (random over 100K ints, no-return -> fire-and-forget).
//   tmp[b*CAP..] : u32 (dst&127)<<24 | src
// ---------------------------------------------------------------------------
__global__ __launch_bounds__(512) void p2_part(const int* __restrict__ src,
                                               const int* __restrict__ dst,
                                               int* __restrict__ cursor_d,
                                               int* __restrict__ deg_src,
                                               unsigned int* __restrict__ tmp) {
    __shared__ int cd[NB];
    __shared__ int bd[NB];
    int t = threadIdx.x;
    for (int j = t; j < NB; j += 512) cd[j] = 0;
    __syncthreads();
    int tb = blockIdx.x * TILE;
    // --- pass A: count ---
    #pragma unroll 4
    for (int i = 0; i < 32; ++i) {
        int e = tb + i * 512 + t;
        if (e < E_EDGES) {
            atomicAdd(&cd[dst[e] >> 7], 1);
            atomicAdd(&deg_src[src[e]], 1);
        }
    }
    __syncthreads();
    // --- reserve contiguous runs ---
    for (int j = t; j < NB; j += 512) {
        int c = cd[j];
        bd[j] = j * CAP + (c ? atomicAdd(&cursor_d[j], c) : 0);
        cd[j] = 0;
    }
    __syncthreads();
    // --- pass B: write (re-read src/dst, L2-hot) ---
    #pragma unroll 4
    for (int i = 0; i < 32; ++i) {
        int e = tb + i * 512 + t;
        if (e < E_EDGES) {
            int s = src[e], d = dst[e];
            int db = d >> 7;
            int p = atomicAdd(&cd[db], 1);
            tmp[bd[db] + p] = ((unsigned int)(d & 127) << 24) | (unsigned int)s;
        }
    }
}

// ---------------------------------------------------------------------------
// GEMM (bf16 MFMA), 256 rows/block, 4 M-tiles per wave. Writes h0b (bf16,
// channel-ordered, for teleport term) AND h8 with norm_src pre-folded.
// h8 byte layout is INTERLEAVED: byte 2i = channel i, byte 2i+1 = channel
// i+32 (i in 0..31) -> one ushort gather per lane yields channels (c2, c2+32).
// ---------------------------------------------------------------------------
__global__ __launch_bounds__(256) void gemm_kernel(const float* __restrict__ A,
                                                   const float* __restrict__ W,
                                                   const float* __restrict__ bias,
                                                   const int* __restrict__ deg_src,
                                                   unsigned short* __restrict__ h0b,
                                                   unsigned char* __restrict__ h8) {
    __shared__ unsigned short Wl[64 * 520];   // 66560 B

    const int tid  = threadIdx.x;
    const int w    = tid >> 6;
    const int lane = tid & 63;
    const int cl   = lane & 15;
    const int quad = lane >> 4;
    const int row0 = blockIdx.x * 256;

    #pragma unroll 8
    for (int j = 0; j < 32; ++j) {
        int e4 = (j * 256 + tid) * 4;
        float4 wv = *reinterpret_cast<const float4*>(&W[e4]);
        int c = e4 >> 9;
        int k = e4 & 511;
        unsigned short* d = &Wl[c * 520 + k];
        d[0] = f2bf(wv.x); d[1] = f2bf(wv.y); d[2] = f2bf(wv.z); d[3] = f2bf(wv.w);
    }
    __syncthreads();

    const float* aptr[4];
    #pragma unroll
    for (int mt = 0; mt < 4; ++mt) {
        int arow = row0 + mt * 64 + w * 16 + cl;
        if (arow >= N_NODES) arow = N_NODES - 1;
        aptr[mt] = A + (size_t)arow * F_IN + quad * 8;
    }

    f32x4 acc0[4], acc1[4], acc2[4], acc3[4];
    #pragma unroll
    for (int mt = 0; mt < 4; ++mt) {
        acc0[mt] = (f32x4){0.f, 0.f, 0.f, 0.f};
        acc1[mt] = (f32x4){0.f, 0.f, 0.f, 0.f};
        acc2[mt] = (f32x4){0.f, 0.f, 0.f, 0.f};
        acc3[mt] = (f32x4){0.f, 0.f, 0.f, 0.f};
    }

    for (int k0 = 0; k0 < F_IN; k0 += 32) {
        bf16x8 af[4];
        #pragma unroll
        for (int mt = 0; mt < 4; ++mt) {
            float4 p = *reinterpret_cast<const float4*>(aptr[mt] + k0);
            float4 q = *reinterpret_cast<const float4*>(aptr[mt] + k0 + 4);
            af[mt][0] = (__bf16)p.x; af[mt][1] = (__bf16)p.y;
            af[mt][2] = (__bf16)p.z; af[mt][3] = (__bf16)p.w;
            af[mt][4] = (__bf16)q.x; af[mt][5] = (__bf16)q.y;
            af[mt][6] = (__bf16)q.z; af[mt][7] = (__bf16)q.w;
        }

        const unsigned short* wb = &Wl[k0 + quad * 8];
        bf16x8 b0 = *reinterpret_cast<const bf16x8*>(wb + (cl +  0) * 520);
        bf16x8 b1 = *reinterpret_cast<const bf16x8*>(wb + (cl + 16) * 520);
        bf16x8 b2 = *reinterpret_cast<const bf16x8*>(wb + (cl + 32) * 520);
        bf16x8 b3 = *reinterpret_cast<const bf16x8*>(wb + (cl + 48) * 520);

        #pragma unroll
        for (int mt = 0; mt < 4; ++mt) {
            acc0[mt] = __builtin_amdgcn_mfma_f32_16x16x32_bf16(af[mt], b0, acc0[mt], 0, 0, 0);
            acc1[mt] = __builtin_amdgcn_mfma_f32_16x16x32_bf16(af[mt], b1, acc1[mt], 0, 0, 0);
            acc2[mt] = __builtin_amdgcn_mfma_f32_16x16x32_bf16(af[mt], b2, acc2[mt], 0, 0, 0);
            acc3[mt] = __builtin_amdgcn_mfma_f32_16x16x32_bf16(af[mt], b3, acc3[mt], 0, 0, 0);
        }
    }

    float bias0 = bias[cl +  0];
    float bias1 = bias[cl + 16];
    float bias2 = bias[cl + 32];
    float bias3 = bias[cl + 48];
    #pragma unroll
    for (int mt = 0; mt < 4; ++mt) {
        #pragma unroll
        for (int r = 0; r < 4; ++r) {
            int row = row0 + mt * 64 + w * 16 + quad * 4 + r;
            if (row < N_NODES) {
                float v0 = acc0[mt][r] + bias0;   // channel cl
                float v1 = acc1[mt][r] + bias1;   // channel cl+16
                float v2 = acc2[mt][r] + bias2;   // channel cl+32
                float v3 = acc3[mt][r] + bias3;   // channel cl+48
                unsigned short* o = &h0b[(size_t)row * C_OUT + cl];
                o[ 0] = f2bf(v0);
                o[16] = f2bf(v1);
                o[32] = f2bf(v2);
                o[48] = f2bf(v3);
                int dg = deg_src[row];
                float ns = rsqrtf((float)(dg < 1 ? 1 : dg));
                unsigned char* o8 = &h8[(size_t)row * C_OUT];
                // interleaved: byte 2i = ch i, byte 2i+1 = ch i+32
                o8[2 * cl     ] = f32_to_fp8(v0 * ns);   // ch cl
                o8[2 * cl + 32] = f32_to_fp8(v1 * ns);   // ch cl+16 -> byte 2(cl+16)
                o8[2 * cl +  1] = f32_to_fp8(v2 * ns);   // ch cl+32
                o8[2 * cl + 33] = f32_to_fp8(v3 * ns);   // ch cl+48
            }
        }
    }
}

// ---------------------------------------------------------------------------
// agg: block b owns the 128 nodes [128b, 128b+128). NO fp32 LDS atomics
// (rounds 1/3/4: fp32 LDS atomicAdd is lane-serialized ~260cy/edge -> 1.3ms).
// Instead: build a per-block CSR in LDS with the PROVEN-fast primitives
// (int histogram atomics + prefix scan + int-cursor scatter, = p3's pattern),
// then each wave register-accumulates its 16 nodes with the PROVEN gather
// pattern (16 edges in flight, 32 lanes x 2 channels via interleaved h8).
// LDS: 20.5KB es + 2KB aux -> 4 blocks/CU (wave-capped).
// ---------------------------------------------------------------------------
__global__ __launch_bounds__(512, 4) void agg_kernel(const unsigned int* __restrict__ tmp,
                                                     const int* __restrict__ cursor_d,
                                                     const unsigned char* __restrict__ h8,
                                                     const unsigned short* __restrict__ h0b,
                                                     float* __restrict__ out) {
    __shared__ int es[CAP];        // 20480 B: within-block CSR edge srcs
    __shared__ int cnt[128];
    __shared__ int off[128];
    __shared__ int lc[128];
    __shared__ int sscan[128];

    int t = threadIdx.x;
    int b = blockIdx.x;

    if (t < 128) { cnt[t] = 0; lc[t] = 0; }
    __syncthreads();

    int nE = cursor_d[b];
    if (nE > CAP) nE = CAP;
    const unsigned int* te = tmp + (size_t)b * CAP;

    // pass 1: in-degree histogram (int LDS atomics, p3-proven)
    for (int e = t; e < nE; e += 512)
        atomicAdd(&cnt[te[e] >> 24], 1);
    __syncthreads();

    // exclusive prefix scan over 128 counters
    if (t < 128) sscan[t] = cnt[t];
    __syncthreads();
    #pragma unroll
    for (int o = 1; o < 128; o <<= 1) {
        int add = (t < 128 && t >= o) ? sscan[t - o] : 0;
        __syncthreads();
        if (t < 128) sscan[t] += add;
        __syncthreads();
    }
    if (t < 128) off[t] = sscan[t] - cnt[t];
    __syncthreads();

    // pass 2: scatter edge srcs into LDS CSR (int cursor atomics + ds_write)
    for (int e = t; e < nE; e += 512) {
        unsigned int v = te[e];
        int dl = v >> 24;
        int p = atomicAdd(&lc[dl], 1);
        es[off[dl] + p] = (int)(v & 0xFFFFFFu);
    }
    __syncthreads();

    // per-wave register-accumulating gather: wave w owns nodes [16w, 16w+16)
    int w    = t >> 6;
    int lane = t & 63;
    int half = lane >> 5;          // edge slot parity
    int c2   = lane & 31;          // channel pair (c2, c2+32)
    const unsigned short* h8p = reinterpret_cast<const unsigned short*>(h8); // row stride 32

    for (int r = 0; r < 16; ++r) {
        int nl   = (w << 4) + r;
        int node = (b << 7) + nl;
        int beg  = off[nl];
        int deg  = cnt[nl];
        int end  = beg + deg;
        float ax = 0.f, ay = 0.f;

        int base = beg;
        for (; base + 16 <= end; base += 16) {
            int e0 = base + half;
            int s0 = es[e0 +  0];
            int s1 = es[e0 +  2];
            int s2 = es[e0 +  4];
            int s3 = es[e0 +  6];
            int s4 = es[e0 +  8];
            int s5 = es[e0 + 10];
            int s6 = es[e0 + 12];
            int s7 = es[e0 + 14];
            unsigned short u0 = h8p[s0 * 32 + c2];
            unsigned short u1 = h8p[s1 * 32 + c2];
            unsigned short u2 = h8p[s2 * 32 + c2];
            unsigned short u3 = h8p[s3 * 32 + c2];
            unsigned short u4 = h8p[s4 * 32 + c2];
            unsigned short u5 = h8p[s5 * 32 + c2];
            unsigned short u6 = h8p[s6 * 32 + c2];
            unsigned short u7 = h8p[s7 * 32 + c2];
            f32x2 f0 = fp8x2_to_f32(u0);
            f32x2 f1 = fp8x2_to_f32(u1);
            f32x2 f2 = fp8x2_to_f32(u2);
            f32x2 f3 = fp8x2_to_f32(u3);
            f32x2 f4 = fp8x2_to_f32(u4);
            f32x2 f5 = fp8x2_to_f32(u5);
            f32x2 f6 = fp8x2_to_f32(u6);
            f32x2 f7 = fp8x2_to_f32(u7);
            ax += (f0[0] + f1[0]) + (f2[0] + f3[0]) + (f4[0] + f5[0]) + (f6[0] + f7[0]);
            ay += (f0[1] + f1[1]) + (f2[1] + f3[1]) + (f4[1] + f5[1]) + (f6[1] + f7[1]);
        }
        for (int e = base + half; e < end; e += 2) {
            int s = es[e];
            f32x2 f = fp8x2_to_f32(h8p[s * 32 + c2]);
            ax += f[0];
            ay += f[1];
        }

        ax += __shfl(ax, lane ^ 32, 64);
        ay += __shfl(ay, lane ^ 32, 64);

        if (half == 0 && node < N_NODES) {
            float nd = rsqrtf((float)(deg < 1 ? 1 : deg));
            float hx = bf2f(h0b[(size_t)node * C_OUT + c2]);
            float hy = bf2f(h0b[(size_t)node * C_OUT + c2 + 32]);
            out[(size_t)node * C_OUT + c2]      = 0.8f * nd * ax + 0.2f * hx;
            out[(size_t)node * C_OUT + c2 + 32] = 0.8f * nd * ay + 0.2f * hy;
        }
    }
}

// ---------------------------------------------------------------------------
extern "C" void kernel_launch(void* const* d_in, const int* in_sizes, int n_in,
                              void* d_out, int out_size, void* d_ws, size_t ws_size,
                              hipStream_t stream) {
    const float* in_feat = (const float*)d_in[0];   // [N, 512]
    const float* W       = (const float*)d_in[1];   // [64, 512]
    const float* bias    = (const float*)d_in[2];   // [64]
    const int*   src     = (const int*)d_in[3];     // [E]
    const int*   dst     = (const int*)d_in[4];     // [E]
    float* out = (float*)d_out;                     // [N, 64]

    // workspace layout (no aliasing; ~36MB of ~800MB):
    char* p = (char*)d_ws;
    unsigned short* h0b = (unsigned short*)p;  p += (size_t)N_NODES * C_OUT * 2;   // 12.8MB
    unsigned char*  h8  = (unsigned char*)p;   p += (size_t)N_NODES * C_OUT;       // 6.4MB
    unsigned int*   tmp = (unsigned int*)p;    p += (size_t)NB * CAP * 4;          // 16MB
    int*   deg_src  = (int*)p;                 p += (size_t)N_NODES * 4;           // 0.4MB
    int*   cursor_d = (int*)p;

    zero_kernel<<<(N_NODES + 511) / 512, 512, 0, stream>>>(deg_src, cursor_d);
    p2_part<<<NTILE, 512, 0, stream>>>(src, dst, cursor_d, deg_src, tmp);
    gemm_kernel<<<(N_NODES + 255) / 256, 256, 0, stream>>>(in_feat, W, bias,
                                                           deg_src, h0b, h8);
    agg_kernel<<<NB, 512, 0, stream>>>(tmp, cursor_d, h8, h0b, out);
}